// Round 1
// baseline (925.557 us; speedup 1.0000x reference)
//
#include <hip/hip_runtime.h>
#include <hip/hip_bf16.h>
#include <stdint.h>

// Problem constants
#define DIN   4096
#define DOUT  4096
#define RANK  16
#define NSUB  4
#define MTOT  8192            // B*S = 4*2048
#define LDK   4160            // 4096 + 5*?? -> 4096 + 64 sub-adapter cols; 4160 = 130*32
#define KTAIL 64              // NSUB*RANK

typedef __attribute__((ext_vector_type(8)))  short    short8;   // 8 bf16 (4 VGPRs)
typedef __attribute__((ext_vector_type(4)))  float    floatx4;
typedef __attribute__((ext_vector_type(8)))  unsigned short ushort8;
typedef __attribute__((ext_vector_type(4)))  unsigned short ushort4v;

static __device__ __forceinline__ unsigned short f2bf(float f) {
    unsigned int u = __float_as_uint(f);
    unsigned int r = (u + 0x7FFFu + ((u >> 16) & 1u)) >> 16;   // RNE
    return (unsigned short)r;
}

static __device__ __forceinline__ void async_copy16(const unsigned short* g, unsigned short* l) {
    __builtin_amdgcn_global_load_lds(
        (const __attribute__((address_space(1))) unsigned int*)g,
        (__attribute__((address_space(3))) unsigned int*)l,
        16, 0, 0);
}

// ---------------------------------------------------------------------------
// Kernel 1: build X_cat [MTOT][LDK] bf16.
//   cols 0..4095: bf16(x)
//   cols 4096+j*16+r: 2 * relu(x . wgate_j) * (x . sub_A[j][r])   (fp32 math)
// 4 tokens per block, 256 threads.
// ---------------------------------------------------------------------------
__global__ __launch_bounds__(256) void build_x_kernel(
    const float* __restrict__ x,
    const float* __restrict__ sub_wgate,   // [NSUB][DIN]
    const float* __restrict__ sub_A,       // [NSUB][RANK][DIN]
    unsigned short* __restrict__ Xc)
{
    __shared__ float xrow[4][DIN];
    __shared__ float vals[4][68];

    const int t  = threadIdx.x;
    const int m0 = blockIdx.x * 4;

    // stage 4 token rows (16384 floats = 4096 float4)
    const float4* xg = (const float4*)(x + (size_t)m0 * DIN);
    float4* xs = (float4*)(&xrow[0][0]);
#pragma unroll
    for (int i = 0; i < 16; ++i) xs[t + 256 * i] = xg[t + 256 * i];
    __syncthreads();

    // write bf16 main part: 2048 chunks of 8 elements
#pragma unroll
    for (int i = 0; i < 8; ++i) {
        int chunk = t + 256 * i;           // 0..2047
        int e  = chunk * 8;                // element in [0,16384)
        int tk = e >> 12;                  // /4096
        int c  = e & 4095;
        const float* src = &xrow[tk][c];
        ushort8 v;
#pragma unroll
        for (int q = 0; q < 8; ++q) v[q] = f2bf(src[q]);
        *(ushort8*)(Xc + (size_t)(m0 + tk) * LDK + c) = v;
    }

    // 68 dot products per token: o<64 -> sub_A row o; o>=64 -> wgate row (o-64)
    const int l = t & 63;
    const int w = t >> 6;
#pragma unroll 1
    for (int idx = 0; idx < 17; ++idx) {
        int o = w + 4 * idx;               // 0..67
        const float* vec = (o < 64) ? (sub_A + (size_t)o * DIN)
                                    : (sub_wgate + (size_t)(o - 64) * DIN);
        const float4* v4 = (const float4*)vec;
#pragma unroll 1
        for (int tk = 0; tk < 4; ++tk) {
            const float4* x4 = (const float4*)xrow[tk];
            float s = 0.f;
#pragma unroll 4
            for (int i = 0; i < 16; ++i) {
                float4 a = x4[l + 64 * i];
                float4 b = v4[l + 64 * i];
                s += a.x * b.x + a.y * b.y + a.z * b.z + a.w * b.w;
            }
#pragma unroll
            for (int off = 32; off > 0; off >>= 1) s += __shfl_down(s, off, 64);
            if (l == 0) vals[tk][o] = s;
        }
    }
    __syncthreads();

    // gated tail: 4 tokens x 64 cols
    {
        int tk = t >> 6;
        int c  = t & 63;
        int j  = c >> 4;
        float g = fmaxf(vals[tk][64 + j], 0.f);
        float val = 2.0f * g * vals[tk][c];
        Xc[(size_t)(m0 + tk) * LDK + DIN + c] = f2bf(val);
    }
}

// ---------------------------------------------------------------------------
// Kernel 2: build W_cat [DOUT][LDK] bf16.
//   cols 0..4095: bf16( W[o][i] + 2 * sum_r base_B[o][r]*base_A[r][i] )
//   cols 4096+j*16+r: bf16( sub_B[j][o][r] )
// 16 output rows per block, 256 threads.
// ---------------------------------------------------------------------------
__global__ __launch_bounds__(256) void build_w_kernel(
    const float* __restrict__ W,        // [DOUT][DIN]
    const float* __restrict__ base_A,   // [RANK][DIN]
    const float* __restrict__ base_B,   // [DOUT][RANK]
    const float* __restrict__ sub_B,    // [NSUB][DOUT][RANK]
    unsigned short* __restrict__ Wc)
{
    __shared__ float Ach[RANK][1024];
    __shared__ float bBs[256];

    const int t  = threadIdx.x;
    const int o0 = blockIdx.x * 16;

    bBs[t] = base_B[(size_t)o0 * RANK + t];   // 16 rows x 16 r

    for (int cc = 0; cc < DIN; cc += 1024) {
        __syncthreads();   // protect previous chunk (and bBs on first iter)
        // stage base_A[0..15][cc..cc+1023]: 4096 float4
#pragma unroll
        for (int i = 0; i < 16; ++i) {
            int f4 = t + 256 * i;            // 0..4095
            int r  = f4 >> 8;                // 256 float4 per row
            int c4 = f4 & 255;
            ((float4*)Ach[r])[c4] = ((const float4*)(base_A + (size_t)r * DIN + cc))[c4];
        }
        __syncthreads();

#pragma unroll 1
        for (int o = 0; o < 16; ++o) {
            float4 acc = ((const float4*)(W + (size_t)(o0 + o) * DIN + cc))[t];
#pragma unroll
            for (int r = 0; r < RANK; ++r) {
                float s = 2.0f * bBs[o * 16 + r];
                float4 a = ((const float4*)Ach[r])[t];
                acc.x += s * a.x; acc.y += s * a.y; acc.z += s * a.z; acc.w += s * a.w;
            }
            ushort4v v;
            v[0] = f2bf(acc.x); v[1] = f2bf(acc.y); v[2] = f2bf(acc.z); v[3] = f2bf(acc.w);
            *(ushort4v*)(Wc + (size_t)(o0 + o) * LDK + cc + t * 4) = v;
        }
    }

    // tail: 16 o x 64 c values
#pragma unroll
    for (int i = 0; i < 4; ++i) {
        int v = t + 256 * i;                 // 0..1023
        int o = v >> 6;
        int c = v & 63;
        int j = c >> 4;
        int r = c & 15;
        float s = sub_B[((size_t)j * DOUT + (o0 + o)) * RANK + r];
        Wc[(size_t)(o0 + o) * LDK + DIN + c] = f2bf(s);
    }
}

// ---------------------------------------------------------------------------
// Kernel 3: out[M][N] = X_cat @ W_cat^T + bias   (bf16 MFMA, fp32 accum)
// 128x128 tile / block, 256 threads = 4 waves (2x2), BK=32, K=4160.
// ---------------------------------------------------------------------------
__global__ __launch_bounds__(256) void gemm_kernel(
    const unsigned short* __restrict__ Xc,
    const unsigned short* __restrict__ Wc,
    const float* __restrict__ bias,
    float* __restrict__ out)
{
    __shared__ unsigned short As[128 * 32];
    __shared__ unsigned short Bs[128 * 32];

    const int t  = threadIdx.x;
    const int l  = t & 63;
    const int w  = t >> 6;
    const int wm = w >> 1;
    const int wn = w & 1;
    const int m0 = blockIdx.y * 128;
    const int n0 = blockIdx.x * 128;

    floatx4 acc[4][4] = {};

    const int srow = t >> 2;              // 0..63
    const int skc  = (t & 3) * 8;
    const unsigned short* gA = Xc + (size_t)(m0 + srow) * LDK + skc;
    const unsigned short* gB = Wc + (size_t)(n0 + srow) * LDK + skc;
    unsigned short* lA = &As[t * 8];
    unsigned short* lB = &Bs[t * 8];

    const int kq   = (l >> 4) * 8;        // k offset of this lane's quad
    const int lane16 = l & 15;

    for (int kk = 0; kk < LDK; kk += 32) {
        async_copy16(gA + kk, lA);
        async_copy16(gA + kk + (size_t)64 * LDK, lA + 64 * 32);
        async_copy16(gB + kk, lB);
        async_copy16(gB + kk + (size_t)64 * LDK, lB + 64 * 32);
        __syncthreads();   // compiler emits vmcnt(0) drain before s_barrier

        short8 af[4], bf[4];
#pragma unroll
        for (int i = 0; i < 4; ++i) {
            af[i] = *(const short8*)&As[(wm * 64 + i * 16 + lane16) * 32 + kq];
            bf[i] = *(const short8*)&Bs[(wn * 64 + i * 16 + lane16) * 32 + kq];
        }
#pragma unroll
        for (int i = 0; i < 4; ++i)
#pragma unroll
            for (int j = 0; j < 4; ++j)
                acc[i][j] = __builtin_amdgcn_mfma_f32_16x16x32_bf16(af[i], bf[j], acc[i][j], 0, 0, 0);
        __syncthreads();
    }

    // epilogue: C/D layout col = lane&15, row = (lane>>4)*4 + reg
    const int row_l = (l >> 4) * 4;
#pragma unroll
    for (int j = 0; j < 4; ++j) {
        int gcol = n0 + wn * 64 + j * 16 + lane16;
        float bv = bias[gcol];
#pragma unroll
        for (int i = 0; i < 4; ++i) {
            int grow = m0 + wm * 64 + i * 16 + row_l;
            size_t base = (size_t)grow * DOUT + gcol;
            out[base]            = acc[i][j][0] + bv;
            out[base + DOUT]     = acc[i][j][1] + bv;
            out[base + 2 * DOUT] = acc[i][j][2] + bv;
            out[base + 3 * DOUT] = acc[i][j][3] + bv;
        }
    }
}

// ---------------------------------------------------------------------------
extern "C" void kernel_launch(void* const* d_in, const int* in_sizes, int n_in,
                              void* d_out, int out_size, void* d_ws, size_t ws_size,
                              hipStream_t stream) {
    const float* x         = (const float*)d_in[0];
    const float* base_W    = (const float*)d_in[1];
    const float* base_b    = (const float*)d_in[2];
    const float* base_A    = (const float*)d_in[3];
    const float* base_B    = (const float*)d_in[4];
    const float* sub_wgate = (const float*)d_in[5];
    const float* sub_A     = (const float*)d_in[6];
    const float* sub_B     = (const float*)d_in[7];
    float* out = (float*)d_out;

    // workspace layout (bf16): X_cat [8192][4160], W_cat [4096][4160]  (~98 MiB)
    unsigned short* Xc = (unsigned short*)d_ws;
    unsigned short* Wc = Xc + (size_t)MTOT * LDK;

    build_x_kernel<<<MTOT / 4, 256, 0, stream>>>(x, sub_wgate, sub_A, Xc);
    build_w_kernel<<<DOUT / 16, 256, 0, stream>>>(base_W, base_A, base_B, sub_B, Wc);
    gemm_kernel<<<dim3(DOUT / 128, MTOT / 128), 256, 0, stream>>>(Xc, Wc, base_b, out);
}

// Round 2
// 787.220 us; speedup vs baseline: 1.1757x; 1.1757x over previous
//
#include <hip/hip_runtime.h>
#include <hip/hip_bf16.h>
#include <stdint.h>

// Problem constants
#define DIN   4096
#define DOUT  4096
#define RANK  16
#define NSUB  4
#define MTOT  8192            // B*S = 4*2048
#define LDK   4160            // 4096 + 64 sub-adapter cols; 4160 = 130*32
#define KTAIL 64              // NSUB*RANK
#define NV    80              // 64 sub_A rows + 4 gate rows + 12 zero pad

typedef __attribute__((ext_vector_type(8)))  short    short8;   // 8 bf16 (4 VGPRs)
typedef __attribute__((ext_vector_type(4)))  float    floatx4;
typedef __attribute__((ext_vector_type(8)))  unsigned short ushort8;
typedef __attribute__((ext_vector_type(4)))  unsigned short ushort4v;

static __device__ __forceinline__ unsigned short f2bf(float f) {
    unsigned int u = __float_as_uint(f);
    unsigned int r = (u + 0x7FFFu + ((u >> 16) & 1u)) >> 16;   // RNE
    return (unsigned short)r;
}

static __device__ __forceinline__ void async_copy16(const unsigned short* g, unsigned short* l) {
    __builtin_amdgcn_global_load_lds(
        (const __attribute__((address_space(1))) unsigned int*)g,
        (__attribute__((address_space(3))) unsigned int*)l,
        16, 0, 0);
}

// ---------------------------------------------------------------------------
// Kernel 0: build Vc [NV][DIN] bf16: rows 0..63 = sub_A (flat [64][DIN]),
// rows 64..67 = sub_wgate, rows 68..79 = 0 (ws is poisoned 0xAA!).
// ---------------------------------------------------------------------------
__global__ __launch_bounds__(256) void build_v_kernel(
    const float* __restrict__ sub_wgate,
    const float* __restrict__ sub_A,
    unsigned short* __restrict__ Vc)
{
    const int t = threadIdx.x;
    const int row = blockIdx.x;      // 0..79
    const float* src = (row < 64) ? (sub_A + (size_t)row * DIN)
                     : (row < 68) ? (sub_wgate + (size_t)(row - 64) * DIN)
                     : nullptr;
#pragma unroll
    for (int i = 0; i < 4; ++i) {
        int c4 = t + 256 * i;          // float4 index, 0..1023
        ushort4v v;
        if (src) {
            float4 a = ((const float4*)src)[c4];
            v[0] = f2bf(a.x); v[1] = f2bf(a.y); v[2] = f2bf(a.z); v[3] = f2bf(a.w);
        } else {
            v[0] = v[1] = v[2] = v[3] = 0;
        }
        *(ushort4v*)(Vc + (size_t)row * DIN + c4 * 4) = v;
    }
}

// ---------------------------------------------------------------------------
// Kernel 1: fused build of X_cat [MTOT][LDK] bf16.
//   cols 0..4095: bf16(x)   (single HBM pass over x)
//   cols 4096+c:  2 * relu(P[tok][64+(c>>4)]) * P[tok][c],
//       where P = x_bf16 @ Vc^T computed with MFMA from the same LDS staging.
// 64 tokens per block, 256 threads = 4 waves. LDS stride padded (264) so the
// MFMA fragment reads are a free 2-way bank alias instead of 16-way.
// ---------------------------------------------------------------------------
#define BXK 256
#define LDA 264
__global__ __launch_bounds__(256) void build_x_kernel(
    const float* __restrict__ x,
    const unsigned short* __restrict__ Vc,
    unsigned short* __restrict__ Xc)
{
    __shared__ char smem[(64 + NV) * LDA * 2];           // 76032 B
    unsigned short* As = (unsigned short*)smem;          // [64][LDA]
    unsigned short* Bs = (unsigned short*)(smem + 64 * LDA * 2);  // [NV][LDA]
    float* P = (float*)smem;                             // [64][NV], reused after k-loop

    const int t  = threadIdx.x;
    const int l  = t & 63;
    const int w  = t >> 6;
    const int m0 = blockIdx.x * 64;
    const int lane16 = l & 15;
    const int kq     = (l >> 4) * 8;

    floatx4 acc[5] = {};

    for (int cc = 0; cc < DIN; cc += BXK) {
        // stage x chunk [64][256]: fp32 -> bf16 -> LDS + global Xc
#pragma unroll
        for (int i = 0; i < 16; ++i) {
            int f4 = t + 256 * i;        // 0..4095
            int tr = f4 >> 6;
            int c4 = f4 & 63;
            float4 a = ((const float4*)(x + (size_t)(m0 + tr) * DIN + cc))[c4];
            ushort4v v;
            v[0] = f2bf(a.x); v[1] = f2bf(a.y); v[2] = f2bf(a.z); v[3] = f2bf(a.w);
            *(ushort4v*)&As[tr * LDA + c4 * 4] = v;
            *(ushort4v*)(Xc + (size_t)(m0 + tr) * LDK + cc + c4 * 4) = v;
        }
        // stage Vc chunk [80][256] (bf16, L2-resident)
#pragma unroll
        for (int i = 0; i < 10; ++i) {
            int idx = t + 256 * i;       // ushort8 index, 0..2559
            int vr  = idx >> 5;          // 32 x ushort8 per 256-col row
            int c8  = idx & 31;
            ushort8 v = *(const ushort8*)(Vc + (size_t)vr * DIN + cc + c8 * 8);
            *(ushort8*)&Bs[vr * LDA + c8 * 8] = v;
        }
        __syncthreads();

        // MFMA: wave w owns token rows w*16..w*16+15, all 5 n-tiles
#pragma unroll
        for (int ks = 0; ks < 8; ++ks) {
            short8 af = *(const short8*)&As[(w * 16 + lane16) * LDA + ks * 32 + kq];
#pragma unroll
            for (int n = 0; n < 5; ++n) {
                short8 bf = *(const short8*)&Bs[(n * 16 + lane16) * LDA + ks * 32 + kq];
                acc[n] = __builtin_amdgcn_mfma_f32_16x16x32_bf16(af, bf, acc[n], 0, 0, 0);
            }
        }
        __syncthreads();
    }

    // dump P[64][NV] to LDS (C/D layout: col=lane&15, row=(l>>4)*4+reg)
#pragma unroll
    for (int n = 0; n < 5; ++n)
#pragma unroll
        for (int r = 0; r < 4; ++r)
            P[(w * 16 + (l >> 4) * 4 + r) * NV + n * 16 + lane16] = acc[n][r];
    __syncthreads();

    // gated tail: 64 tokens x 64 cols
#pragma unroll
    for (int i = 0; i < 16; ++i) {
        int v  = t + 256 * i;            // 0..4095
        int tr = v >> 6;
        int c  = v & 63;
        int j  = c >> 4;
        float g = fmaxf(P[tr * NV + 64 + j], 0.f);
        Xc[(size_t)(m0 + tr) * LDK + DIN + c] = f2bf(2.0f * g * P[tr * NV + c]);
    }
}

// ---------------------------------------------------------------------------
// Kernel 2: build W_cat [DOUT][LDK] bf16.
//   cols 0..4095: bf16( W[o][i] + 2 * sum_r base_B[o][r]*base_A[r][i] )
//   cols 4096+j*16+r: bf16( sub_B[j][o][r] )
// 16 output rows per block, 256 threads.
// ---------------------------------------------------------------------------
__global__ __launch_bounds__(256) void build_w_kernel(
    const float* __restrict__ W,        // [DOUT][DIN]
    const float* __restrict__ base_A,   // [RANK][DIN]
    const float* __restrict__ base_B,   // [DOUT][RANK]
    const float* __restrict__ sub_B,    // [NSUB][DOUT][RANK]
    unsigned short* __restrict__ Wc)
{
    __shared__ float Ach[RANK][1024];
    __shared__ float bBs[256];

    const int t  = threadIdx.x;
    const int o0 = blockIdx.x * 16;

    bBs[t] = base_B[(size_t)o0 * RANK + t];   // 16 rows x 16 r

    for (int cc = 0; cc < DIN; cc += 1024) {
        __syncthreads();   // protect previous chunk (and bBs on first iter)
#pragma unroll
        for (int i = 0; i < 16; ++i) {
            int f4 = t + 256 * i;            // 0..4095
            int r  = f4 >> 8;
            int c4 = f4 & 255;
            ((float4*)Ach[r])[c4] = ((const float4*)(base_A + (size_t)r * DIN + cc))[c4];
        }
        __syncthreads();

#pragma unroll 1
        for (int o = 0; o < 16; ++o) {
            float4 acc = ((const float4*)(W + (size_t)(o0 + o) * DIN + cc))[t];
#pragma unroll
            for (int r = 0; r < RANK; ++r) {
                float s = 2.0f * bBs[o * 16 + r];
                float4 a = ((const float4*)Ach[r])[t];
                acc.x += s * a.x; acc.y += s * a.y; acc.z += s * a.z; acc.w += s * a.w;
            }
            ushort4v v;
            v[0] = f2bf(acc.x); v[1] = f2bf(acc.y); v[2] = f2bf(acc.z); v[3] = f2bf(acc.w);
            *(ushort4v*)(Wc + (size_t)(o0 + o) * LDK + cc + t * 4) = v;
        }
    }

    // tail: 16 o x 64 c values
#pragma unroll
    for (int i = 0; i < 4; ++i) {
        int v = t + 256 * i;                 // 0..1023
        int o = v >> 6;
        int c = v & 63;
        int j = c >> 4;
        int r = c & 15;
        float s = sub_B[((size_t)j * DOUT + (o0 + o)) * RANK + r];
        Wc[(size_t)(o0 + o) * LDK + DIN + c] = f2bf(s);
    }
}

// ---------------------------------------------------------------------------
// Kernel 3: out[M][N] = X_cat @ W_cat^T + bias   (bf16 MFMA, fp32 accum)
// 128x128 tile / block, 256 threads = 4 waves (2x2), BK=32, K=4160.
// ---------------------------------------------------------------------------
__global__ __launch_bounds__(256) void gemm_kernel(
    const unsigned short* __restrict__ Xc,
    const unsigned short* __restrict__ Wc,
    const float* __restrict__ bias,
    float* __restrict__ out)
{
    __shared__ unsigned short As[128 * 32];
    __shared__ unsigned short Bs[128 * 32];

    const int t  = threadIdx.x;
    const int l  = t & 63;
    const int w  = t >> 6;
    const int wm = w >> 1;
    const int wn = w & 1;
    const int m0 = blockIdx.y * 128;
    const int n0 = blockIdx.x * 128;

    floatx4 acc[4][4] = {};

    const int srow = t >> 2;              // 0..63
    const int skc  = (t & 3) * 8;
    const unsigned short* gA = Xc + (size_t)(m0 + srow) * LDK + skc;
    const unsigned short* gB = Wc + (size_t)(n0 + srow) * LDK + skc;
    unsigned short* lA = &As[t * 8];
    unsigned short* lB = &Bs[t * 8];

    const int kq   = (l >> 4) * 8;        // k offset of this lane's quad
    const int lane16 = l & 15;

    for (int kk = 0; kk < LDK; kk += 32) {
        async_copy16(gA + kk, lA);
        async_copy16(gA + kk + (size_t)64 * LDK, lA + 64 * 32);
        async_copy16(gB + kk, lB);
        async_copy16(gB + kk + (size_t)64 * LDK, lB + 64 * 32);
        __syncthreads();

        short8 af[4], bf[4];
#pragma unroll
        for (int i = 0; i < 4; ++i) {
            af[i] = *(const short8*)&As[(wm * 64 + i * 16 + lane16) * 32 + kq];
            bf[i] = *(const short8*)&Bs[(wn * 64 + i * 16 + lane16) * 32 + kq];
        }
#pragma unroll
        for (int i = 0; i < 4; ++i)
#pragma unroll
            for (int j = 0; j < 4; ++j)
                acc[i][j] = __builtin_amdgcn_mfma_f32_16x16x32_bf16(af[i], bf[j], acc[i][j], 0, 0, 0);
        __syncthreads();
    }

    // epilogue: C/D layout col = lane&15, row = (lane>>4)*4 + reg
    const int row_l = (l >> 4) * 4;
#pragma unroll
    for (int j = 0; j < 4; ++j) {
        int gcol = n0 + wn * 64 + j * 16 + lane16;
        float bv = bias[gcol];
#pragma unroll
        for (int i = 0; i < 4; ++i) {
            int grow = m0 + wm * 64 + i * 16 + row_l;
            size_t base = (size_t)grow * DOUT + gcol;
            out[base]            = acc[i][j][0] + bv;
            out[base + DOUT]     = acc[i][j][1] + bv;
            out[base + 2 * DOUT] = acc[i][j][2] + bv;
            out[base + 3 * DOUT] = acc[i][j][3] + bv;
        }
    }
}

// ---------------------------------------------------------------------------
extern "C" void kernel_launch(void* const* d_in, const int* in_sizes, int n_in,
                              void* d_out, int out_size, void* d_ws, size_t ws_size,
                              hipStream_t stream) {
    const float* x         = (const float*)d_in[0];
    const float* base_W    = (const float*)d_in[1];
    const float* base_b    = (const float*)d_in[2];
    const float* base_A    = (const float*)d_in[3];
    const float* base_B    = (const float*)d_in[4];
    const float* sub_wgate = (const float*)d_in[5];
    const float* sub_A     = (const float*)d_in[6];
    const float* sub_B     = (const float*)d_in[7];
    float* out = (float*)d_out;

    // workspace layout (bf16): X_cat [8192][4160], W_cat [4096][4160], Vc [80][4096]
    unsigned short* Xc = (unsigned short*)d_ws;
    unsigned short* Wc = Xc + (size_t)MTOT * LDK;
    unsigned short* Vc = Wc + (size_t)DOUT * LDK;

    build_v_kernel<<<NV, 256, 0, stream>>>(sub_wgate, sub_A, Vc);
    build_x_kernel<<<MTOT / 64, 256, 0, stream>>>(x, Vc, Xc);
    build_w_kernel<<<DOUT / 16, 256, 0, stream>>>(base_W, base_A, base_B, sub_B, Wc);
    gemm_kernel<<<dim3(DOUT / 128, MTOT / 128), 256, 0, stream>>>(Xc, Wc, base_b, out);
}

// Round 3
// 626.222 us; speedup vs baseline: 1.4780x; 1.2571x over previous
//
#include <hip/hip_runtime.h>
#include <hip/hip_bf16.h>
#include <stdint.h>

// Problem constants
#define DIN   4096
#define DOUT  4096
#define RANK  16
#define NSUB  4
#define MTOT  8192            // B*S = 4*2048
#define LDK   4160            // 4096 + 64 sub-adapter cols; 4160 = 130*32
#define KTAIL 64              // NSUB*RANK
#define NV    80              // 64 sub_A rows + 4 gate rows + 12 zero pad

typedef __attribute__((ext_vector_type(8)))  short    short8;   // 8 bf16 (4 VGPRs)
typedef __attribute__((ext_vector_type(4)))  float    floatx4;
typedef __attribute__((ext_vector_type(8)))  unsigned short ushort8;
typedef __attribute__((ext_vector_type(4)))  unsigned short ushort4v;

static __device__ __forceinline__ unsigned short f2bf(float f) {
    unsigned int u = __float_as_uint(f);
    unsigned int r = (u + 0x7FFFu + ((u >> 16) & 1u)) >> 16;   // RNE
    return (unsigned short)r;
}

static __device__ __forceinline__ void async_copy16(const unsigned short* g, unsigned short* l) {
    __builtin_amdgcn_global_load_lds(
        (const __attribute__((address_space(1))) unsigned int*)g,
        (__attribute__((address_space(3))) unsigned int*)l,
        16, 0, 0);
}

// ---------------------------------------------------------------------------
// Kernel 0: build Vc [NV][DIN] bf16: rows 0..63 = sub_A (flat [64][DIN]),
// rows 64..67 = sub_wgate, rows 68..79 = 0 (ws is poisoned 0xAA!).
// ---------------------------------------------------------------------------
__global__ __launch_bounds__(256) void build_v_kernel(
    const float* __restrict__ sub_wgate,
    const float* __restrict__ sub_A,
    unsigned short* __restrict__ Vc)
{
    const int t = threadIdx.x;
    const int row = blockIdx.x;      // 0..79
    const float* src = (row < 64) ? (sub_A + (size_t)row * DIN)
                     : (row < 68) ? (sub_wgate + (size_t)(row - 64) * DIN)
                     : nullptr;
#pragma unroll
    for (int i = 0; i < 4; ++i) {
        int c4 = t + 256 * i;          // float4 index, 0..1023
        ushort4v v;
        if (src) {
            float4 a = ((const float4*)src)[c4];
            v[0] = f2bf(a.x); v[1] = f2bf(a.y); v[2] = f2bf(a.z); v[3] = f2bf(a.w);
        } else {
            v[0] = v[1] = v[2] = v[3] = 0;
        }
        *(ushort4v*)(Vc + (size_t)row * DIN + c4 * 4) = v;
    }
}

// ---------------------------------------------------------------------------
// Kernel 1 (v2): fused build of X_cat [MTOT][LDK] bf16.
//   cols 0..4095: bf16(x)   (single HBM pass over x)
//   cols 4096+c:  2 * relu(P[tok][64+(c>>4)]) * P[tok][c],
//       where P = x_bf16 @ Vc^T via MFMA from the same LDS staging.
// 16 tokens/block -> grid 512 (2-3 blocks/CU). The 4 waves k-split each
// 256-wide chunk 4-ways (2 MFMA k-steps each) and reduce partial P in LDS.
// LDS stride 264 breaks the 512B-stride bank pattern; staging stores are
// ushort8 (16B) so writes span all banks.
// ---------------------------------------------------------------------------
#define BXK 256
#define LDA 264
__global__ __launch_bounds__(256) void build_x_kernel(
    const float* __restrict__ x,
    const unsigned short* __restrict__ Vc,
    unsigned short* __restrict__ Xc)
{
    __shared__ char smem[(16 + NV) * LDA * 2];           // 50688 B
    unsigned short* As = (unsigned short*)smem;          // [16][LDA]
    unsigned short* Bs = As + 16 * LDA;                  // [NV][LDA]
    float* Pp = (float*)smem;                            // [4][16][NV], reused

    const int t  = threadIdx.x;
    const int l  = t & 63;
    const int w  = t >> 6;        // wave = k-quarter
    const int m0 = blockIdx.x * 16;
    const int lane16 = l & 15;
    const int kq     = (l >> 4) * 8;

    floatx4 acc[5] = {};

    for (int cc = 0; cc < DIN; cc += BXK) {
        // stage x chunk [16][256]: fp32 -> bf16 -> LDS + global Xc (2 u8/thread)
#pragma unroll
        for (int i = 0; i < 2; ++i) {
            int u8 = t + 256 * i;        // 0..511
            int tr = u8 >> 5;            // 32 ushort8 per row
            int c8 = u8 & 31;
            const float4* src = (const float4*)(x + (size_t)(m0 + tr) * DIN + cc + c8 * 8);
            float4 a = src[0], b = src[1];
            ushort8 v;
            v[0] = f2bf(a.x); v[1] = f2bf(a.y); v[2] = f2bf(a.z); v[3] = f2bf(a.w);
            v[4] = f2bf(b.x); v[5] = f2bf(b.y); v[6] = f2bf(b.z); v[7] = f2bf(b.w);
            *(ushort8*)&As[tr * LDA + c8 * 8] = v;
            *(ushort8*)(Xc + (size_t)(m0 + tr) * LDK + cc + c8 * 8) = v;
        }
        // stage Vc chunk [80][256] (bf16, L2-resident): 10 u8/thread
#pragma unroll
        for (int i = 0; i < 10; ++i) {
            int idx = t + 256 * i;       // 0..2559
            int vr  = idx >> 5;
            int c8  = idx & 31;
            ushort8 v = *(const ushort8*)(Vc + (size_t)vr * DIN + cc + c8 * 8);
            *(ushort8*)&Bs[vr * LDA + c8 * 8] = v;
        }
        __syncthreads();

        // MFMA: wave w handles k-steps {2w, 2w+1} of the 8 in this chunk
#pragma unroll
        for (int s = 0; s < 2; ++s) {
            int ks = w * 2 + s;
            short8 af = *(const short8*)&As[lane16 * LDA + ks * 32 + kq];
#pragma unroll
            for (int n = 0; n < 5; ++n) {
                short8 bf = *(const short8*)&Bs[(n * 16 + lane16) * LDA + ks * 32 + kq];
                acc[n] = __builtin_amdgcn_mfma_f32_16x16x32_bf16(af, bf, acc[n], 0, 0, 0);
            }
        }
        __syncthreads();
    }

    // dump partial P (C/D layout: col=lane&15, row=(l>>4)*4+reg)
#pragma unroll
    for (int n = 0; n < 5; ++n)
#pragma unroll
        for (int r = 0; r < 4; ++r)
            Pp[(w * 16 + (l >> 4) * 4 + r) * NV + n * 16 + lane16] = acc[n][r];
    __syncthreads();

    // gated tail: 16 tokens x 64 cols, summing the 4 k-partials
#pragma unroll
    for (int i = 0; i < 4; ++i) {
        int v  = t + 256 * i;            // 0..1023
        int tr = v >> 6;
        int c  = v & 63;
        int j  = c >> 4;
        float ps = 0.f, gs = 0.f;
#pragma unroll
        for (int q = 0; q < 4; ++q) {
            ps += Pp[(q * 16 + tr) * NV + c];
            gs += Pp[(q * 16 + tr) * NV + 64 + j];
        }
        Xc[(size_t)(m0 + tr) * LDK + DIN + c] = f2bf(2.0f * fmaxf(gs, 0.f) * ps);
    }
}

// ---------------------------------------------------------------------------
// Kernel 2 (v2): build W_cat [DOUT][LDK] bf16 — streaming, no big LDS.
//   cols 0..4095: bf16( W[o][i] + 2 * sum_r base_B[o][r]*base_A[r][i] )
//   cols 4096+j*16+r: bf16( sub_B[j][o][r] )
// Block = 8 o-rows x 1024 cols; each thread owns one float4 column-quad for
// all 8 rows, so each base_A read (L2-resident) is reused 8x. Grid 2048.
// ---------------------------------------------------------------------------
__global__ __launch_bounds__(256) void build_w_kernel(
    const float* __restrict__ W,        // [DOUT][DIN]
    const float* __restrict__ base_A,   // [RANK][DIN]
    const float* __restrict__ base_B,   // [DOUT][RANK]
    const float* __restrict__ sub_B,    // [NSUB][DOUT][RANK]
    unsigned short* __restrict__ Wc)
{
    __shared__ float bBs[8 * RANK];

    const int t  = threadIdx.x;
    const int o0 = (blockIdx.x >> 2) * 8;
    const int cc = (blockIdx.x & 3) * 1024;
    const int q  = (cc >> 2) + t;        // float4 index into a DIN row

    if (t < 128) bBs[t] = 2.0f * base_B[(size_t)o0 * RANK + t];
    __syncthreads();

    float4 acc[8];
#pragma unroll
    for (int o = 0; o < 8; ++o)
        acc[o] = ((const float4*)(W + (size_t)(o0 + o) * DIN))[q];

#pragma unroll
    for (int r = 0; r < RANK; ++r) {
        float4 a = ((const float4*)(base_A + (size_t)r * DIN))[q];
#pragma unroll
        for (int o = 0; o < 8; ++o) {
            float s = bBs[o * RANK + r];
            acc[o].x += s * a.x; acc[o].y += s * a.y;
            acc[o].z += s * a.z; acc[o].w += s * a.w;
        }
    }

#pragma unroll
    for (int o = 0; o < 8; ++o) {
        ushort4v v;
        v[0] = f2bf(acc[o].x); v[1] = f2bf(acc[o].y);
        v[2] = f2bf(acc[o].z); v[3] = f2bf(acc[o].w);
        *(ushort4v*)(Wc + (size_t)(o0 + o) * LDK + q * 4) = v;
    }

    // tail: one col-chunk per o-group writes the 8 x 64 sub_B cols
    if ((blockIdx.x & 3) == 0) {
#pragma unroll
        for (int i = 0; i < 2; ++i) {
            int v = t + 256 * i;             // 0..511
            int o = v >> 6;
            int c = v & 63;
            int j = c >> 4;
            int r = c & 15;
            float s = sub_B[((size_t)j * DOUT + (o0 + o)) * RANK + r];
            Wc[(size_t)(o0 + o) * LDK + DIN + c] = f2bf(s);
        }
    }
}

// ---------------------------------------------------------------------------
// Kernel 3: out[M][N] = X_cat @ W_cat^T + bias   (bf16 MFMA, fp32 accum)
// 128x128 tile / block, 256 threads = 4 waves (2x2), BK=32, K=4160.
// (unchanged from R2 to isolate the prep-kernel rewrite)
// ---------------------------------------------------------------------------
__global__ __launch_bounds__(256) void gemm_kernel(
    const unsigned short* __restrict__ Xc,
    const unsigned short* __restrict__ Wc,
    const float* __restrict__ bias,
    float* __restrict__ out)
{
    __shared__ unsigned short As[128 * 32];
    __shared__ unsigned short Bs[128 * 32];

    const int t  = threadIdx.x;
    const int l  = t & 63;
    const int w  = t >> 6;
    const int wm = w >> 1;
    const int wn = w & 1;
    const int m0 = blockIdx.y * 128;
    const int n0 = blockIdx.x * 128;

    floatx4 acc[4][4] = {};

    const int srow = t >> 2;              // 0..63
    const int skc  = (t & 3) * 8;
    const unsigned short* gA = Xc + (size_t)(m0 + srow) * LDK + skc;
    const unsigned short* gB = Wc + (size_t)(n0 + srow) * LDK + skc;
    unsigned short* lA = &As[t * 8];
    unsigned short* lB = &Bs[t * 8];

    const int kq   = (l >> 4) * 8;        // k offset of this lane's quad
    const int lane16 = l & 15;

    for (int kk = 0; kk < LDK; kk += 32) {
        async_copy16(gA + kk, lA);
        async_copy16(gA + kk + (size_t)64 * LDK, lA + 64 * 32);
        async_copy16(gB + kk, lB);
        async_copy16(gB + kk + (size_t)64 * LDK, lB + 64 * 32);
        __syncthreads();

        short8 af[4], bf[4];
#pragma unroll
        for (int i = 0; i < 4; ++i) {
            af[i] = *(const short8*)&As[(wm * 64 + i * 16 + lane16) * 32 + kq];
            bf[i] = *(const short8*)&Bs[(wn * 64 + i * 16 + lane16) * 32 + kq];
        }
#pragma unroll
        for (int i = 0; i < 4; ++i)
#pragma unroll
            for (int j = 0; j < 4; ++j)
                acc[i][j] = __builtin_amdgcn_mfma_f32_16x16x32_bf16(af[i], bf[j], acc[i][j], 0, 0, 0);
        __syncthreads();
    }

    // epilogue: C/D layout col = lane&15, row = (lane>>4)*4 + reg
    const int row_l = (l >> 4) * 4;
#pragma unroll
    for (int j = 0; j < 4; ++j) {
        int gcol = n0 + wn * 64 + j * 16 + lane16;
        float bv = bias[gcol];
#pragma unroll
        for (int i = 0; i < 4; ++i) {
            int grow = m0 + wm * 64 + i * 16 + row_l;
            size_t base = (size_t)grow * DOUT + gcol;
            out[base]            = acc[i][j][0] + bv;
            out[base + DOUT]     = acc[i][j][1] + bv;
            out[base + 2 * DOUT] = acc[i][j][2] + bv;
            out[base + 3 * DOUT] = acc[i][j][3] + bv;
        }
    }
}

// ---------------------------------------------------------------------------
extern "C" void kernel_launch(void* const* d_in, const int* in_sizes, int n_in,
                              void* d_out, int out_size, void* d_ws, size_t ws_size,
                              hipStream_t stream) {
    const float* x         = (const float*)d_in[0];
    const float* base_W    = (const float*)d_in[1];
    const float* base_b    = (const float*)d_in[2];
    const float* base_A    = (const float*)d_in[3];
    const float* base_B    = (const float*)d_in[4];
    const float* sub_wgate = (const float*)d_in[5];
    const float* sub_A     = (const float*)d_in[6];
    const float* sub_B     = (const float*)d_in[7];
    float* out = (float*)d_out;

    // workspace layout (bf16): X_cat [8192][4160], W_cat [4096][4160], Vc [80][4096]
    unsigned short* Xc = (unsigned short*)d_ws;
    unsigned short* Wc = Xc + (size_t)MTOT * LDK;
    unsigned short* Vc = Wc + (size_t)DOUT * LDK;

    build_v_kernel<<<NV, 256, 0, stream>>>(sub_wgate, sub_A, Vc);
    build_x_kernel<<<MTOT / 16, 256, 0, stream>>>(x, Vc, Xc);
    build_w_kernel<<<(DOUT / 8) * 4, 256, 0, stream>>>(base_W, base_A, base_B, sub_B, Wc);
    gemm_kernel<<<dim3(DOUT / 128, MTOT / 128), 256, 0, stream>>>(Xc, Wc, base_b, out);
}